// Round 6
// baseline (58.555 us; speedup 1.0000x reference)
//
#include <hip/hip_runtime.h>

typedef __bf16 bf16x8 __attribute__((ext_vector_type(8)));
typedef float f32x16 __attribute__((ext_vector_type(16)));
typedef int i32x2 __attribute__((ext_vector_type(2)));
typedef unsigned int u32;

#define NCH 4   // 4 chunks of 128 keys = 512-key window

static __device__ __forceinline__ u32 cvt_pk_bf16(float lo, float hi) {
    u32 r;
    asm("v_cvt_pk_bf16_f32 %0, %1, %2" : "=v"(r) : "v"(lo), "v"(hi));
    return r;
}

__global__ __launch_bounds__(512, 4)
void local_attn_kernel(const float* __restrict__ qg, const float* __restrict__ kg,
                       const float* __restrict__ vg, float* __restrict__ og)
{
    // K: [buf][key 0..127][dim], 16B-slot swizzle (slot ^= key&7) -> conflict-free b128 r/w
    __shared__ __align__(16) __bf16 sK[2][128][64];
    // V: [buf][dim 0..63][keypair 0..63] u32 (keys 2k,2k+1 packed);
    // col = 4*slot + j, slot = G ^ (dim&7) ^ ((dim>>2)&7): read conflict-free, write 2-way
    __shared__ __align__(16) u32 sVp[2][64][64];

    const int bid = ((blockIdx.x & 7) << 6) | (blockIdx.x >> 3);  // XCD swizzle (bijective)
    const int bh = bid >> 4, bi = bid & 15;
    const int tid = threadIdx.x, w = tid >> 6;
    const int lane = tid & 63, l31 = lane & 31, h = lane >> 5;

    const long long base = (long long)bh << 18;           // *4096*64
    const float* qp = qg + base + ((long long)bi << 14);  // *256*64
    const float* kp = kg + base + (((long long)(bi - 1)) << 14);
    const float* vp = vg + base + (((long long)(bi - 1)) << 14);
    float*       op = og + base + ((long long)bi << 14);

    // ---- Q B-frags, pre-scaled by 0.125*log2(e); lane: query=w*32+l31, dim=ks*16+8h+i
    bf16x8 qf[4];
    {
        const float QS = 0.18033688011112042f;   // (1/8)*log2(e): exp(s/8)=2^(s*QS)
        const float* qrow = qp + (w * 32 + l31) * 64 + 8 * h;
#pragma unroll
        for (int ks = 0; ks < 4; ++ks) {
            float4 f0 = *(const float4*)(qrow + ks * 16);
            float4 f1 = *(const float4*)(qrow + ks * 16 + 4);
            bf16x8 t;
            t[0] = (__bf16)(f0.x * QS); t[1] = (__bf16)(f0.y * QS);
            t[2] = (__bf16)(f0.z * QS); t[3] = (__bf16)(f0.w * QS);
            t[4] = (__bf16)(f1.x * QS); t[5] = (__bf16)(f1.y * QS);
            t[6] = (__bf16)(f1.z * QS); t[7] = (__bf16)(f1.w * QS);
            qf[ks] = t;
        }
    }

    f32x16 o0, o1;
#pragma unroll
    for (int i = 0; i < 16; ++i) { o0[i] = 0.f; o1[i] = 0.f; }
    float lsum = 0.f;

    // staging maps (coalesced global); 2 tasks per thread per chunk for K and V
    const int skey = tid >> 3, stg = tid & 7;              // K: key, 16B dim-group
    const int kslot = (stg ^ (skey & 7)) << 3;             // (skey+64)&7 == skey&7
    const int vkp = tid >> 4, vd0 = (tid & 15) * 4;        // V: keypair, 4 dims

    const int c0 = (bi == 0) ? 2 : 0;      // bucket 0: first 256 window keys are pad
    const int qpos = w * 32 + l31;

    int cur = 0;
    union F4 { float4 v; float f[4]; };
    F4 kr[2][2], vr[2][2];

    auto stage_load = [&](int c) {
#pragma unroll
        for (int a = 0; a < 2; ++a) {
            const float* ks_ = kp + (c * 128 + skey + 64 * a) * 64 + stg * 8;
            kr[a][0].v = *(const float4*)ks_;
            kr[a][1].v = *(const float4*)(ks_ + 4);
            const float* vs_ = vp + (c * 128 + 2 * (vkp + 32 * a)) * 64 + vd0;
            vr[a][0].v = *(const float4*)vs_;
            vr[a][1].v = *(const float4*)(vs_ + 64);
        }
    };
    auto stage_write = [&](int buf) {
#pragma unroll
        for (int a = 0; a < 2; ++a) {
            union { u32 u[4]; bf16x8 b; } kv;
            kv.u[0] = cvt_pk_bf16(kr[a][0].f[0], kr[a][0].f[1]);
            kv.u[1] = cvt_pk_bf16(kr[a][0].f[2], kr[a][0].f[3]);
            kv.u[2] = cvt_pk_bf16(kr[a][1].f[0], kr[a][1].f[1]);
            kv.u[3] = cvt_pk_bf16(kr[a][1].f[2], kr[a][1].f[3]);
            *(bf16x8*)&sK[buf][skey + 64 * a][kslot] = kv.b;
            const int kp2 = vkp + 32 * a, G = kp2 >> 2, j = kp2 & 3;
#pragma unroll
            for (int i = 0; i < 4; ++i) {
                const int row = vd0 + i;
                const int sl = G ^ (row & 7) ^ ((row >> 2) & 7);
                sVp[buf][row][(sl << 2) + j] = cvt_pk_bf16(vr[a][0].f[i], vr[a][1].f[i]);
            }
        }
    };

    stage_load(c0);
    stage_write(0);

    for (int c = c0; c < NCH; ++c) {
        __syncthreads();                       // buf `cur` ready for all waves
        const bool pf = (c + 1 < NCH);         // block-uniform
        if (pf) stage_load(c + 1);             // issue early: latency hides under compute

        const int kbase_c = c * 128;
#pragma unroll
        for (int kt = 0; kt < 4; ++kt) {
            const int kb0 = kbase_c + kt * 32;
            if (kb0 > 32 * w + 287) continue;  // wave-uniform causal skip

            // ---- QK^T swapped: S[key][query] = mfma(K_A, Q_B) ----
            const int key = kt * 32 + l31;
            const int ksw = key & 7;
            bf16x8 kfa[4];
#pragma unroll
            for (int ks = 0; ks < 4; ++ks)
                kfa[ks] = *(const bf16x8*)&sK[cur][key][((ks * 2 + h) ^ ksw) << 3];
            f32x16 s;
#pragma unroll
            for (int i = 0; i < 16; ++i) s[i] = 0.f;
#pragma unroll
            for (int ks = 0; ks < 4; ++ks)
                s = __builtin_amdgcn_mfma_f32_32x32x16_bf16(kfa[ks], qf[ks], s, 0, 0, 0);

            // ---- exp2 (scores bounded; no max-tracking), mask only boundary kt ----
            float pv[16];
            const int jb = kb0 + 4 * h;
            if (kb0 + 31 <= 32 * w + 256) {    // fully unmasked for this wave
#pragma unroll
                for (int r = 0; r < 16; ++r) {
                    pv[r] = __builtin_amdgcn_exp2f(s[r]);
                    lsum += pv[r];
                }
            } else {
#pragma unroll
                for (int r = 0; r < 16; ++r) {
                    const int j = jb + (r & 3) + 8 * (r >> 2);
                    float e = __builtin_amdgcn_exp2f(s[r]);
                    pv[r] = (j > qpos + 256) ? 0.f : e;
                    lsum += pv[r];
                }
            }

            // ---- P -> bf16 A-frags in-register (cvt_pk + permlane32_swap) ----
            u32 wds[8];
#pragma unroll
            for (int m = 0; m < 8; ++m)
                wds[m] = cvt_pk_bf16(pv[2 * m], pv[2 * m + 1]);

#pragma unroll
            for (int kis = 0; kis < 2; ++kis) {
                i32x2 r02 = __builtin_amdgcn_permlane32_swap(
                    (int)wds[4 * kis + 0], (int)wds[4 * kis + 2], false, false);
                i32x2 r13 = __builtin_amdgcn_permlane32_swap(
                    (int)wds[4 * kis + 1], (int)wds[4 * kis + 3], false, false);
                union { u32 u[4]; bf16x8 b; } pu;
                pu.u[0] = (u32)r02.x; pu.u[1] = (u32)r13.x;
                pu.u[2] = (u32)r02.y; pu.u[3] = (u32)r13.y;

                const int G = (kt * 2 + kis) * 2 + h;
                const int sl = G ^ (l31 & 7) ^ ((l31 >> 2) & 7);  // same for row l31, 32+l31
                bf16x8 vb0 = *(const bf16x8*)&sVp[cur][l31][sl << 2];
                bf16x8 vb1 = *(const bf16x8*)&sVp[cur][32 + l31][sl << 2];
                o0 = __builtin_amdgcn_mfma_f32_32x32x16_bf16(pu.b, vb0, o0, 0, 0, 0);
                o1 = __builtin_amdgcn_mfma_f32_32x32x16_bf16(pu.b, vb1, o1, 0, 0, 0);
            }
        }

        if (pf) stage_write(cur ^ 1);          // write late: after compute, before barrier
        cur ^= 1;
    }

    // ---- epilogue: combine half-sums, broadcast per-query inv, normalize, store ----
    lsum += __shfl_xor(lsum, 32, 64);
    const float inv = 1.0f / lsum;     // valid at lane l31 for query w*32+l31
#pragma unroll
    for (int r = 0; r < 16; ++r) {
        const int qr = (r & 3) + 8 * (r >> 2) + 4 * h;   // query row of C reg r
        const float iq = __shfl(inv, qr, 64);
        float* orow = op + (w * 32 + qr) * 64;
        orow[l31]      = o0[r] * iq;
        orow[32 + l31] = o1[r] * iq;
    }
}

extern "C" void kernel_launch(void* const* d_in, const int* in_sizes, int n_in,
                              void* d_out, int out_size, void* d_ws, size_t ws_size,
                              hipStream_t stream) {
    const float* q = (const float*)d_in[0];
    const float* k = (const float*)d_in[1];
    const float* v = (const float*)d_in[2];
    float* out = (float*)d_out;
    local_attn_kernel<<<dim3(512), dim3(512), 0, stream>>>(q, k, v, out);
}

// Round 7
// 34.153 us; speedup vs baseline: 1.7145x; 1.7145x over previous
//
#include <hip/hip_runtime.h>

typedef __bf16 bf16x8 __attribute__((ext_vector_type(8)));
typedef float f32x16 __attribute__((ext_vector_type(16)));
typedef int i32x2 __attribute__((ext_vector_type(2)));
typedef unsigned int u32;

#define NCH 8   // 8 chunks of 64 keys = 512-key window

static __device__ __forceinline__ u32 cvt_pk_bf16(float lo, float hi) {
    u32 r;
    asm("v_cvt_pk_bf16_f32 %0, %1, %2" : "=v"(r) : "v"(lo), "v"(hi));
    return r;
}

__global__ __launch_bounds__(512, 4)
void local_attn_kernel(const float* __restrict__ qg, const float* __restrict__ kg,
                       const float* __restrict__ vg, float* __restrict__ og)
{
    // K: [buf][key][dim], 16B-slot swizzle (slot ^= key&7) -> conflict-free b128 r/w
    __shared__ __align__(16) __bf16 sK[2][64][64];
    // V: [buf][dim][keypair] u32; col = 4*sl + j, sl = kq ^ (dim&7) ^ ((dim>>2)&7)
    // (round-6-validated): write 2-way, read ~2-way per phase
    __shared__ __align__(16) u32 sVp[2][64][32];

    const int bid = ((blockIdx.x & 7) << 6) | (blockIdx.x >> 3);  // XCD swizzle (bijective)
    const int bh = bid >> 4, bi = bid & 15;
    const int tid = threadIdx.x, w = tid >> 6;
    const int lane = tid & 63, l31 = lane & 31, h = lane >> 5;

    const long long base = (long long)bh << 18;           // *4096*64
    const float* qp = qg + base + ((long long)bi << 14);  // *256*64
    const float* kp = kg + base + (((long long)(bi - 1)) << 14);
    const float* vp = vg + base + (((long long)(bi - 1)) << 14);
    float*       op = og + base + ((long long)bi << 14);

    // ---- Q B-frags, pre-scaled by 0.125*log2(e); lane: query=w*32+l31, dim=ks*16+8h+i
    bf16x8 qf[4];
    {
        const float QS = 0.18033688011112042f;   // (1/8)*log2(e): exp(s/8)=2^(s*QS)
        const float* qrow = qp + (w * 32 + l31) * 64 + 8 * h;
#pragma unroll
        for (int ks = 0; ks < 4; ++ks) {
            float4 f0 = *(const float4*)(qrow + ks * 16);
            float4 f1 = *(const float4*)(qrow + ks * 16 + 4);
            bf16x8 t;
            t[0] = (__bf16)(f0.x * QS); t[1] = (__bf16)(f0.y * QS);
            t[2] = (__bf16)(f0.z * QS); t[3] = (__bf16)(f0.w * QS);
            t[4] = (__bf16)(f1.x * QS); t[5] = (__bf16)(f1.y * QS);
            t[6] = (__bf16)(f1.z * QS); t[7] = (__bf16)(f1.w * QS);
            qf[ks] = t;
        }
    }

    f32x16 o0, o1;
#pragma unroll
    for (int i = 0; i < 16; ++i) { o0[i] = 0.f; o1[i] = 0.f; }
    float lsum = 0.f;

    // staging maps (coalesced global)
    const int skey = tid >> 3, stg = tid & 7;              // K: key, 16B dim-group
    const int kslot = (stg ^ (skey & 7)) << 3;
    const int vkp = tid >> 4, vd0 = (tid & 15) * 4;        // V: keypair, 4 dims
    const int vkq = vkp >> 2, vj = vkp & 3;
    const float* kA = kp + skey * 64 + stg * 8;
    const float* vA = vp + (2 * vkp) * 64 + vd0;

    const int c0 = (bi == 0) ? 4 : 0;      // bucket 0: first 256 window keys are pad
    const int qpos = w * 32 + l31;
    const int wlim = 32 * w + 287;

    int cur = 0;
    // T14 staging registers: live only within one barrier interval (16 VGPRs)
    float4 k0r, k1r, v0r, v1r;

#define STAGE_LOAD(c) do {                                   \
        const float* ks_ = kA + (c) * (64 * 64);             \
        k0r = *(const float4*)ks_;                           \
        k1r = *(const float4*)(ks_ + 4);                     \
        const float* vs_ = vA + (c) * (64 * 64);             \
        v0r = *(const float4*)vs_;                           \
        v1r = *(const float4*)(vs_ + 64);                    \
    } while (0)

#define STAGE_WRITE(buf) do {                                                     \
        union { u32 u[4]; bf16x8 b; } kv_;                                        \
        kv_.u[0] = cvt_pk_bf16(k0r.x, k0r.y);                                     \
        kv_.u[1] = cvt_pk_bf16(k0r.z, k0r.w);                                     \
        kv_.u[2] = cvt_pk_bf16(k1r.x, k1r.y);                                     \
        kv_.u[3] = cvt_pk_bf16(k1r.z, k1r.w);                                     \
        *(bf16x8*)&sK[buf][skey][kslot] = kv_.b;                                  \
        {                                                                         \
            const int r0 = vd0,     s0 = vkq ^ (r0 & 7) ^ ((r0 >> 2) & 7);        \
            const int r1 = vd0 + 1, s1 = vkq ^ (r1 & 7) ^ ((r1 >> 2) & 7);        \
            const int r2 = vd0 + 2, s2 = vkq ^ (r2 & 7) ^ ((r2 >> 2) & 7);        \
            const int r3 = vd0 + 3, s3 = vkq ^ (r3 & 7) ^ ((r3 >> 2) & 7);        \
            sVp[buf][r0][(s0 << 2) + vj] = cvt_pk_bf16(v0r.x, v1r.x);             \
            sVp[buf][r1][(s1 << 2) + vj] = cvt_pk_bf16(v0r.y, v1r.y);             \
            sVp[buf][r2][(s2 << 2) + vj] = cvt_pk_bf16(v0r.z, v1r.z);             \
            sVp[buf][r3][(s3 << 2) + vj] = cvt_pk_bf16(v0r.w, v1r.w);             \
        }                                                                         \
    } while (0)

    STAGE_LOAD(c0);
    STAGE_WRITE(0);

    for (int c = c0; c < NCH; ++c) {
        __syncthreads();                       // buf `cur` ready for all waves
        const bool pf = (c + 1 < NCH);         // block-uniform
        if (pf) STAGE_LOAD(c + 1);             // issue early: latency hides under compute

        const int kbase = c * 64;
#pragma unroll
        for (int kt = 0; kt < 2; ++kt) {
            const int kb0 = kbase + 32 * kt;
            if (kb0 > wlim) continue;          // wave-uniform causal skip

            // ---- QK^T swapped: S[key][query] = mfma(K_A, Q_B) ----
            const int key = kt * 32 + l31;
            const int ksw = key & 7;
            bf16x8 kfa[4];
#pragma unroll
            for (int ks = 0; ks < 4; ++ks)
                kfa[ks] = *(const bf16x8*)&sK[cur][key][((ks * 2 + h) ^ ksw) << 3];
            f32x16 s;
#pragma unroll
            for (int i = 0; i < 16; ++i) s[i] = 0.f;
#pragma unroll
            for (int ks = 0; ks < 4; ++ks)
                s = __builtin_amdgcn_mfma_f32_32x32x16_bf16(kfa[ks], qf[ks], s, 0, 0, 0);

            // ---- exp2 (scores bounded; no max-tracking), mask only boundary kt ----
            float pv[16];
            const int jb = kb0 + 4 * h;
            if (kb0 + 31 <= 32 * w + 256) {    // fully unmasked for this wave
#pragma unroll
                for (int r = 0; r < 16; ++r) {
                    pv[r] = __builtin_amdgcn_exp2f(s[r]);
                    lsum += pv[r];
                }
            } else {
#pragma unroll
                for (int r = 0; r < 16; ++r) {
                    const int j = jb + (r & 3) + 8 * (r >> 2);
                    float e = __builtin_amdgcn_exp2f(s[r]);
                    pv[r] = (j > qpos + 256) ? 0.f : e;
                    lsum += pv[r];
                }
            }

            // ---- P -> bf16 A-frags in-register (cvt_pk + permlane32_swap) ----
            u32 wds[8];
#pragma unroll
            for (int m = 0; m < 8; ++m)
                wds[m] = cvt_pk_bf16(pv[2 * m], pv[2 * m + 1]);

#pragma unroll
            for (int kis = 0; kis < 2; ++kis) {
                i32x2 r02 = __builtin_amdgcn_permlane32_swap(
                    (int)wds[4 * kis + 0], (int)wds[4 * kis + 2], false, false);
                i32x2 r13 = __builtin_amdgcn_permlane32_swap(
                    (int)wds[4 * kis + 1], (int)wds[4 * kis + 3], false, false);
                union { u32 u[4]; bf16x8 b; } pu;
                pu.u[0] = (u32)r02.x; pu.u[1] = (u32)r13.x;
                pu.u[2] = (u32)r02.y; pu.u[3] = (u32)r13.y;

                const int G = (kt * 2 + kis) * 2 + h;
                const int sl = G ^ (l31 & 7) ^ ((l31 >> 2) & 7);  // same for rows l31, 32+l31
                bf16x8 vb0 = *(const bf16x8*)&sVp[cur][l31][sl << 2];
                bf16x8 vb1 = *(const bf16x8*)&sVp[cur][32 + l31][sl << 2];
                o0 = __builtin_amdgcn_mfma_f32_32x32x16_bf16(pu.b, vb0, o0, 0, 0, 0);
                o1 = __builtin_amdgcn_mfma_f32_32x32x16_bf16(pu.b, vb1, o1, 0, 0, 0);
            }
        }

        if (pf) STAGE_WRITE(cur ^ 1);          // write late: after compute, before barrier
        cur ^= 1;
    }

    // ---- epilogue: combine half-sums, broadcast per-query inv, normalize, store ----
    lsum += __shfl_xor(lsum, 32, 64);
    const float inv = 1.0f / lsum;     // valid at lane l31 for query w*32+l31
#pragma unroll
    for (int r = 0; r < 16; ++r) {
        const int qr = (r & 3) + 8 * (r >> 2) + 4 * h;   // query row of C reg r
        const float iq = __shfl(inv, qr, 64);
        float* orow = op + (w * 32 + qr) * 64;
        orow[l31]      = o0[r] * iq;
        orow[32 + l31] = o1[r] * iq;
    }
}

extern "C" void kernel_launch(void* const* d_in, const int* in_sizes, int n_in,
                              void* d_out, int out_size, void* d_ws, size_t ws_size,
                              hipStream_t stream) {
    const float* q = (const float*)d_in[0];
    const float* k = (const float*)d_in[1];
    const float* v = (const float*)d_in[2];
    float* out = (float*)d_out;
    local_attn_kernel<<<dim3(512), dim3(512), 0, stream>>>(q, k, v, out);
}